// Round 8
// baseline (212.500 us; speedup 1.0000x reference)
//
#include <hip/hip_runtime.h>
#include <cfloat>

#define NPTS   16384
#define MATOMS 8192
#define CH     16
#define ADIM   6
#define KNN    16
#define GROUPS_PER_BLOCK 8     // 32 lanes per point
#define BIGF   1e10f
#define SLOTS  32              // per-lane LDS candidate capacity (E~4 with tau ~ rank-124)

__device__ __forceinline__ float leakyf(float x) { return x >= 0.0f ? x : 0.2f * x; }

// ---------------------------------------------------------------------------
// Kernel A: per-atom feature MLP t = L3(L2(L1(atomtypes))) + packed pos4
// ---------------------------------------------------------------------------
__global__ void __launch_bounds__(256) prep_kernel(
    const float* __restrict__ atom_xyz,
    const float* __restrict__ atomtypes,
    const int*   __restrict__ atom_batch,
    const float* __restrict__ Wt1, const float* __restrict__ bt1,
    const float* __restrict__ Wt2, const float* __restrict__ bt2,
    const float* __restrict__ Wt3, const float* __restrict__ bt3,
    float4* __restrict__ pos4,
    float*  __restrict__ tbuf,
    int*    __restrict__ abatch)
{
    __shared__ float w1[CH*ADIM], w2[CH*CH], w3[CH*CH], bb1[CH], bb2[CH], bb3[CH];
    const int tid = threadIdx.x;
    if (tid < CH*ADIM) w1[tid] = Wt1[tid];
    if (tid < CH*CH)   { w2[tid] = Wt2[tid]; w3[tid] = Wt3[tid]; }
    if (tid < CH)      { bb1[tid] = bt1[tid]; bb2[tid] = bt2[tid]; bb3[tid] = bt3[tid]; }
    __syncthreads();
    const int m = blockIdx.x * 256 + tid;
    if (m >= MATOMS) return;

    float x[ADIM];
    #pragma unroll
    for (int j = 0; j < ADIM; ++j) x[j] = atomtypes[m*ADIM + j];

    float h0[CH], h1[CH], h2[CH];
    #pragma unroll
    for (int c = 0; c < CH; ++c) {
        float a = 0.0f;
        #pragma unroll
        for (int j = 0; j < ADIM; ++j) a = fmaf(w1[c*ADIM+j], x[j], a);
        h0[c] = leakyf(a + bb1[c]);
    }
    #pragma unroll
    for (int c = 0; c < CH; ++c) {
        float a = 0.0f;
        #pragma unroll
        for (int j = 0; j < CH; ++j) a = fmaf(w2[c*CH+j], h0[j], a);
        h1[c] = leakyf(a + bb2[c]);
    }
    #pragma unroll
    for (int c = 0; c < CH; ++c) {
        float a = 0.0f;
        #pragma unroll
        for (int j = 0; j < CH; ++j) a = fmaf(w3[c*CH+j], h1[j], a);
        h2[c] = leakyf(a + bb3[c]);
    }
    #pragma unroll
    for (int c = 0; c < CH; ++c) tbuf[m*CH + c] = h2[c];

    const float ax = atom_xyz[m*3+0], ay = atom_xyz[m*3+1], az = atom_xyz[m*3+2];
    // np: sum(a*a, -1) = ((ax^2 + ay^2) + az^2), no FMA contraction
    const float a2 = __fadd_rn(__fadd_rn(__fmul_rn(ax,ax), __fmul_rn(ay,ay)), __fmul_rn(az,az));
    pos4[m] = make_float4(ax, ay, az, a2);
    abatch[m] = atom_batch[m];
}

// ---------------------------------------------------------------------------
// Kernel B: 32 lanes per point (8 groups/block, 2048 blocks = 8 blocks/CU).
//   Phase A': per-lane MIN over 1/8 subset (cheap: 2 ops/candidate, 1 reg)
//   tau-select: 16 d-only pop-mins over the 32 lane minima.
//     Validity: each pop removes >=1 lane = >=1 distinct atom with d2<=tau,
//     so after 16 pops >=16 atoms have d2 <= tau  =>  tau >= d16_full.
//     (tau >= BIG -> group-uniform fallback.)
//   Phase B: lean full scan (4x unroll, lazy abatch), append idx to LDS
//   overflow guard: group-or(cnt > SLOTS) or tau>=BIG -> full insert-scan
//   Phase C: exact top-16 via validated insert + lexicographic pop-min merge
//   Epilogue (lower 16 lanes): per-channel contraction + shuffle MLP
// ---------------------------------------------------------------------------
__global__ void __launch_bounds__(256) atom_main_kernel(
    const float* __restrict__ xyz,
    const int*   __restrict__ batch,
    const float4* __restrict__ pos4,
    const float* __restrict__ tbuf,
    const int*   __restrict__ abatch,
    const float* __restrict__ Watt,
    const float* __restrict__ We1, const float* __restrict__ be1,
    const float* __restrict__ We2, const float* __restrict__ be2,
    const float* __restrict__ We3, const float* __restrict__ be3,
    float* __restrict__ out)
{
    // transposed weights: lwXt[j*16+c] = W[c][j]  -> conflict-free lane reads
    __shared__ float lw1t[CH*CH], lw2t[CH*CH], lw3t[CH*CH];
    __shared__ float lb1[CH], lb2[CH], lb3[CH], lwatt[KNN];
    // candidate buffer: [group][slot][lane32] u16, lane-interleaved
    __shared__ unsigned short lbuf[GROUPS_PER_BLOCK * SLOTS * 32];
    const int tid = threadIdx.x;
    lw1t[tid] = We1[(tid & 15)*CH + (tid >> 4)];
    lw2t[tid] = We2[(tid & 15)*CH + (tid >> 4)];
    lw3t[tid] = We3[(tid & 15)*CH + (tid >> 4)];
    if (tid < CH) { lb1[tid] = be1[tid]; lb2[tid] = be2[tid]; lb3[tid] = be3[tid]; lwatt[tid] = Watt[tid]; }
    __syncthreads();

    const int c32 = tid & 31;                       // lane-in-group (scan lane)
    const int g   = tid >> 5;                       // group-in-block
    const int n   = blockIdx.x * GROUPS_PER_BLOCK + g;

    const float px = xyz[n*3+0], py = xyz[n*3+1], pz = xyz[n*3+2];
    // np: sum(x*x, -1) sequential, no FMA
    const float pn2 = __fadd_rn(__fadd_rn(__fmul_rn(px,px), __fmul_rn(py,py)), __fmul_rn(pz,pz));
    const int pb = batch[n];

    // ---- Phase A': per-lane min over 1/8 systematic subset (32 atoms/lane).
    float vmin = FLT_MAX;
    for (int t4 = 0; t4 < 8; ++t4) {
        float4 A[4]; int AB[4];
        #pragma unroll
        for (int u = 0; u < 4; ++u) {
            const int i = ((t4*4 + u)*32 + c32) * 8;
            A[u]  = pos4[i];
            AB[u] = abatch[i];
        }
        #pragma unroll
        for (int u = 0; u < 4; ++u) {
            // np: d2 = (pn2 + a2) - 2*(x@aT); BLAS dot = sequential FMA
            const float dot = fmaf(pz, A[u].z, fmaf(py, A[u].y, __fmul_rn(px, A[u].x)));
            float d2 = __fsub_rn(__fadd_rn(pn2, A[u].w), 2.0f * dot);
            d2 = (AB[u] == pb) ? d2 : BIGF;
            vmin = fminf(vmin, d2);
        }
    }

    // ---- tau-select: 16 d-only pop-mins over the group's 32 lane minima.
    float tau;
    {
        float v = vmin;
        #pragma unroll
        for (int k = 0; k < KNN; ++k) {
            float d = v;
            d = fminf(d, __shfl_xor(d, 1));
            d = fminf(d, __shfl_xor(d, 2));
            d = fminf(d, __shfl_xor(d, 4));
            d = fminf(d, __shfl_xor(d, 8));
            d = fminf(d, __shfl_xor(d, 16));
            tau = d;
            if (v == d) v = FLT_MAX;    // remove popped (ties together: safe)
        }
    }

    // ---- Phase B: lean full scan (256 candidates/lane), 4x unrolled with
    // hoisted loads and lazy abatch. tau >= BIG -> fallback required.
    int cnt = 0;
    unsigned short* seg = &lbuf[g * (SLOTS*32) + c32];
    const int skip = !(tau < BIGF);                 // group-uniform
    if (!skip) {
        for (int t = 0; t < MATOMS/32; t += 4) {
            float4 A[4];
            #pragma unroll
            for (int u = 0; u < 4; ++u) A[u] = pos4[(t+u)*32 + c32];
            #pragma unroll
            for (int u = 0; u < 4; ++u) {
                const int i = (t+u)*32 + c32;
                const float dot = fmaf(pz, A[u].z, fmaf(py, A[u].y, __fmul_rn(px, A[u].x)));
                const float d2 = __fsub_rn(__fadd_rn(pn2, A[u].w), 2.0f * dot);
                if (d2 <= tau) {
                    if (abatch[i] == pb) {
                        if (cnt < SLOTS) seg[cnt*32] = (unsigned short)i;
                        ++cnt;
                    }
                }
            }
        }
    }

    // ---- overflow guard (wave reconverged): group-or over 32 lanes.
    int ovf = skip | (cnt > SLOTS);
    ovf |= __shfl_xor(ovf, 1);
    ovf |= __shfl_xor(ovf, 2);
    ovf |= __shfl_xor(ovf, 4);
    ovf |= __shfl_xor(ovf, 8);
    ovf |= __shfl_xor(ovf, 16);

    float bd[KNN]; int bi[KNN];
    #pragma unroll
    for (int j = 0; j < KNN; ++j) { bd[j] = FLT_MAX; bi[j] = 0x7fffffff; }

    if (ovf) {
        // validated full insert-scan (rare; group-uniform; no cross-lane ops)
        for (int t = 0; t < MATOMS/32; ++t) {
            const int i = t*32 + c32;
            const float4 a = pos4[i];
            const int ab = abatch[i];
            const float dot = fmaf(pz, a.z, fmaf(py, a.y, __fmul_rn(px, a.x)));
            float d2 = __fsub_rn(__fadd_rn(pn2, a.w), 2.0f * dot);
            d2 = (ab == pb) ? d2 : BIGF;
            if (d2 < bd[KNN-1]) {
                float d = d2; int id = i;
                #pragma unroll
                for (int j = 0; j < KNN; ++j) {
                    const bool sw = d < bd[j];
                    const float od = bd[j]; const int oi = bi[j];
                    bd[j] = sw ? d  : bd[j];
                    bi[j] = sw ? id : bi[j];
                    d  = sw ? od : d;
                    id = sw ? oi : id;
                }
            }
        }
    } else {
        // ---- Phase C: exact top-16 of collected (appends were increasing-
        // index, so strict '<' d-only insert is tie-exact).
        for (int s = 0; s < cnt; ++s) {
            const int i = (int)seg[s*32];
            const float4 a = pos4[i];
            const float dot = fmaf(pz, a.z, fmaf(py, a.y, __fmul_rn(px, a.x)));
            const float d2 = __fsub_rn(__fadd_rn(pn2, a.w), 2.0f * dot);
            if (d2 < bd[KNN-1]) {
                float d = d2; int id = i;
                #pragma unroll
                for (int j = 0; j < KNN; ++j) {
                    const bool sw = d < bd[j];
                    const float od = bd[j]; const int oi = bi[j];
                    bd[j] = sw ? d  : bd[j];
                    bi[j] = sw ? id : bi[j];
                    d  = sw ? od : d;
                    id = sw ? oi : id;
                }
            }
        }
    }

    // ---- final merge: 16x pop-min over 32 lanes, lexicographic (d, idx);
    // all lanes receive idxk.
    int idxk[KNN];
    #pragma unroll
    for (int k = 0; k < KNN; ++k) {
        float d = bd[0]; int i = bi[0];
        #pragma unroll
        for (int m = 1; m <= 16; m <<= 1) {
            const float pd = __shfl_xor(d, m);
            const int   pi = __shfl_xor(i, m);
            const bool take = (pd < d) || (pd == d && pi < i);
            d = take ? pd : d;
            i = take ? pi : i;
        }
        idxk[k] = i;
        const bool win = (bd[0] == d) && (bi[0] == i);
        if (win) {
            #pragma unroll
            for (int j = 0; j < KNN-1; ++j) { bd[j] = bd[j+1]; bi[j] = bi[j+1]; }
            bd[KNN-1] = FLT_MAX; bi[KNN-1] = 0x7fffffff;
        }
    }

    // ---- Epilogue on lower 16 lanes of each group (exact validated numerics:
    // sequential k=0..15 accumulation per channel).
    if ((tid & 16) == 0) {
        const int c = tid & 15;                     // channel
        float ac0 = 0.0f, ac1 = 0.0f, ac2 = 0.0f;
        #pragma unroll
        for (int k = 0; k < KNN; ++k) {
            const int j = idxk[k];
            const float4 a = pos4[j];
            const float v0 = __fsub_rn(px, a.x);
            const float v1 = __fsub_rn(py, a.y);
            const float v2 = __fsub_rn(pz, a.z);
            // np: dists = sum(vecs*vecs, -1), sequential, no FMA (recomputed)
            const float dist = __fadd_rn(__fadd_rn(__fmul_rn(v0,v0), __fmul_rn(v1,v1)), __fmul_rn(v2,v2));
            const float w = 1.0f / __fadd_rn(dist, 1e-8f);   // power(x, -1.0)
            const float nv0 = __fmul_rn(v0, w);
            const float nv1 = __fmul_rn(v1, w);
            const float nv2 = __fmul_rn(v2, w);
            const float fc = tbuf[(size_t)j * CH + c];
            const float fw = __fmul_rn(fc, lwatt[k]);
            ac0 = fmaf(nv0, fw, ac0);
            ac1 = fmaf(nv1, fw, ac1);
            ac2 = fmaf(nv2, fw, ac2);
        }
        const float s = __fadd_rn(__fadd_rn(__fmul_rn(ac0,ac0), __fmul_rn(ac1,ac1)),
                                  __fmul_rn(ac2,ac2));
        const float fx = sqrtf(s);

        // output MLP: lane c computes channel c; values shared via width-16 shfl.
        float a1 = 0.0f;
        #pragma unroll
        for (int j = 0; j < CH; ++j) {
            const float fj = __shfl(fx, j, 16);
            a1 = fmaf(lw1t[j*CH + c], fj, a1);
        }
        const float g1 = leakyf(a1 + lb1[c]);

        float a2 = 0.0f;
        #pragma unroll
        for (int j = 0; j < CH; ++j) {
            const float gj = __shfl(g1, j, 16);
            a2 = fmaf(lw2t[j*CH + c], gj, a2);
        }
        const float g2 = leakyf(a2 + lb2[c]);

        float a3 = 0.0f;
        #pragma unroll
        for (int j = 0; j < CH; ++j) {
            const float gj = __shfl(g2, j, 16);
            a3 = fmaf(lw3t[j*CH + c], gj, a3);
        }
        out[(size_t)n*CH + c] = a3 + lb3[c];
    }
}

// ---------------------------------------------------------------------------
extern "C" void kernel_launch(void* const* d_in, const int* in_sizes, int n_in,
                              void* d_out, int out_size, void* d_ws, size_t ws_size,
                              hipStream_t stream)
{
    (void)in_sizes; (void)n_in; (void)out_size; (void)ws_size;
    const float* xyz        = (const float*)d_in[0];
    const float* atom_xyz   = (const float*)d_in[1];
    const float* atomtypes  = (const float*)d_in[2];
    const int*   batch      = (const int*)d_in[3];
    const int*   atom_batch = (const int*)d_in[4];
    const float* Wt1 = (const float*)d_in[5];
    const float* bt1 = (const float*)d_in[6];
    const float* Wt2 = (const float*)d_in[7];
    const float* bt2 = (const float*)d_in[8];
    const float* Wt3 = (const float*)d_in[9];
    const float* bt3 = (const float*)d_in[10];
    const float* Watt = (const float*)d_in[11];
    const float* We1 = (const float*)d_in[12];
    const float* be1 = (const float*)d_in[13];
    const float* We2 = (const float*)d_in[14];
    const float* be2 = (const float*)d_in[15];
    const float* We3 = (const float*)d_in[16];
    const float* be3 = (const float*)d_in[17];

    char* ws = (char*)d_ws;
    float4* pos4  = (float4*)ws;                          // 8192*16  = 131072 B
    float*  tbuf  = (float*)(ws + 131072);                // 8192*64  = 524288 B
    int*    abat  = (int*)(ws + 131072 + 524288);         // 8192*4   =  32768 B
    float*  out   = (float*)d_out;

    hipLaunchKernelGGL(prep_kernel, dim3(MATOMS/256), dim3(256), 0, stream,
                       atom_xyz, atomtypes, atom_batch,
                       Wt1, bt1, Wt2, bt2, Wt3, bt3,
                       pos4, tbuf, abat);
    hipLaunchKernelGGL(atom_main_kernel, dim3(NPTS/GROUPS_PER_BLOCK), dim3(256), 0, stream,
                       xyz, batch, pos4, tbuf, abat,
                       Watt, We1, be1, We2, be2, We3, be3,
                       out);
}

// Round 9
// 154.080 us; speedup vs baseline: 1.3791x; 1.3791x over previous
//
#include <hip/hip_runtime.h>
#include <cfloat>

#define NPTS   16384
#define MATOMS 8192
#define CH     16
#define ADIM   6
#define KNN    16
#define GROUPS_PER_BLOCK 8     // 32 lanes per point
#define BIGF   1e10f
#define SLOTS  16              // per-lane LDS candidate capacity (E~2.8 with 1/4-subset tau)
#define CHUNK  512
#define NCHUNK (MATOMS/CHUNK)  // 16
#define VMIN_CHUNKS 4          // tau subset = first 2048 atoms (contiguous, iid input)

__device__ __forceinline__ float leakyf(float x) { return x >= 0.0f ? x : 0.2f * x; }

// ---------------------------------------------------------------------------
// Kernel A: per-atom feature MLP t = L3(L2(L1(atomtypes))) + packed pos4
// ---------------------------------------------------------------------------
__global__ void __launch_bounds__(256) prep_kernel(
    const float* __restrict__ atom_xyz,
    const float* __restrict__ atomtypes,
    const int*   __restrict__ atom_batch,
    const float* __restrict__ Wt1, const float* __restrict__ bt1,
    const float* __restrict__ Wt2, const float* __restrict__ bt2,
    const float* __restrict__ Wt3, const float* __restrict__ bt3,
    float4* __restrict__ pos4,
    float*  __restrict__ tbuf,
    int*    __restrict__ abatch)
{
    __shared__ float w1[CH*ADIM], w2[CH*CH], w3[CH*CH], bb1[CH], bb2[CH], bb3[CH];
    const int tid = threadIdx.x;
    if (tid < CH*ADIM) w1[tid] = Wt1[tid];
    if (tid < CH*CH)   { w2[tid] = Wt2[tid]; w3[tid] = Wt3[tid]; }
    if (tid < CH)      { bb1[tid] = bt1[tid]; bb2[tid] = bt2[tid]; bb3[tid] = bt3[tid]; }
    __syncthreads();
    const int m = blockIdx.x * 256 + tid;
    if (m >= MATOMS) return;

    float x[ADIM];
    #pragma unroll
    for (int j = 0; j < ADIM; ++j) x[j] = atomtypes[m*ADIM + j];

    float h0[CH], h1[CH], h2[CH];
    #pragma unroll
    for (int c = 0; c < CH; ++c) {
        float a = 0.0f;
        #pragma unroll
        for (int j = 0; j < ADIM; ++j) a = fmaf(w1[c*ADIM+j], x[j], a);
        h0[c] = leakyf(a + bb1[c]);
    }
    #pragma unroll
    for (int c = 0; c < CH; ++c) {
        float a = 0.0f;
        #pragma unroll
        for (int j = 0; j < CH; ++j) a = fmaf(w2[c*CH+j], h0[j], a);
        h1[c] = leakyf(a + bb2[c]);
    }
    #pragma unroll
    for (int c = 0; c < CH; ++c) {
        float a = 0.0f;
        #pragma unroll
        for (int j = 0; j < CH; ++j) a = fmaf(w3[c*CH+j], h1[j], a);
        h2[c] = leakyf(a + bb3[c]);
    }
    #pragma unroll
    for (int c = 0; c < CH; ++c) tbuf[m*CH + c] = h2[c];

    const float ax = atom_xyz[m*3+0], ay = atom_xyz[m*3+1], az = atom_xyz[m*3+2];
    // np: sum(a*a, -1) = ((ax^2 + ay^2) + az^2), no FMA contraction
    const float a2 = __fadd_rn(__fadd_rn(__fmul_rn(ax,ax), __fmul_rn(ay,ay)), __fmul_rn(az,az));
    pos4[m] = make_float4(ax, ay, az, a2);
    abatch[m] = atom_batch[m];
}

// ---------------------------------------------------------------------------
// Kernel B: 32 lanes per point, 8 groups/block, 2048 blocks (8 blocks/CU).
//   All groups in a block share pos4 -> block-cooperative LDS chunk staging.
//   vmin pass (chunks 0..3 = contiguous 2048-atom subset): per-lane min
//   tau-select: 16 d-only pop-mins over 32 lane minima (tau >= d16_full:
//     each pop removes >=1 lane = >=1 distinct valid atom with d2 <= tau)
//   filter pass (all 16 chunks): lean LDS scan, append (d2<=tau) idx to LDS
//   overflow guard: group-or(cnt > SLOTS) or tau>=BIG -> full insert-scan
//   Phase C: exact top-16 via validated insert + lexicographic pop-min merge
//   Epilogue (lower 16 lanes): per-channel contraction + shuffle MLP
// ---------------------------------------------------------------------------
__global__ void __launch_bounds__(256) atom_main_kernel(
    const float* __restrict__ xyz,
    const int*   __restrict__ batch,
    const float4* __restrict__ pos4,
    const float* __restrict__ tbuf,
    const int*   __restrict__ abatch,
    const float* __restrict__ Watt,
    const float* __restrict__ We1, const float* __restrict__ be1,
    const float* __restrict__ We2, const float* __restrict__ be2,
    const float* __restrict__ We3, const float* __restrict__ be3,
    float* __restrict__ out)
{
    // transposed weights: lwXt[j*16+c] = W[c][j]  -> conflict-free lane reads
    __shared__ float lw1t[CH*CH], lw2t[CH*CH], lw3t[CH*CH];
    __shared__ float lb1[CH], lb2[CH], lb3[CH], lwatt[KNN];
    // candidate buffer: [group][slot][lane32] u16, lane-interleaved
    __shared__ unsigned short lbuf[GROUPS_PER_BLOCK * SLOTS * 32];
    // staged atom chunk (shared by all 8 groups)
    __shared__ float4 lpos[CHUNK];
    const int tid = threadIdx.x;
    lw1t[tid] = We1[(tid & 15)*CH + (tid >> 4)];
    lw2t[tid] = We2[(tid & 15)*CH + (tid >> 4)];
    lw3t[tid] = We3[(tid & 15)*CH + (tid >> 4)];
    if (tid < CH) { lb1[tid] = be1[tid]; lb2[tid] = be2[tid]; lb3[tid] = be3[tid]; lwatt[tid] = Watt[tid]; }

    const int c32 = tid & 31;                       // lane-in-group (scan lane)
    const int g   = tid >> 5;                       // group-in-block
    const int n   = blockIdx.x * GROUPS_PER_BLOCK + g;

    const float px = xyz[n*3+0], py = xyz[n*3+1], pz = xyz[n*3+2];
    // np: sum(x*x, -1) sequential, no FMA
    const float pn2 = __fadd_rn(__fadd_rn(__fmul_rn(px,px), __fmul_rn(py,py)), __fmul_rn(pz,pz));
    const int pb = batch[n];

    // ---- vmin pass over staged chunks 0..3 (2048-atom contiguous subset;
    // per-lane 64 atoms, disjoint across lanes, increasing index).
    float vmin = FLT_MAX;
    for (int cb = 0; cb < VMIN_CHUNKS; ++cb) {
        __syncthreads();
        #pragma unroll
        for (int j2 = 0; j2 < CHUNK/256; ++j2) lpos[j2*256 + tid] = pos4[cb*CHUNK + j2*256 + tid];
        __syncthreads();
        #pragma unroll 4
        for (int t = 0; t < CHUNK/32; ++t) {
            const int il = t*32 + c32;
            const float4 a = lpos[il];
            // np: d2 = (pn2 + a2) - 2*(x@aT); BLAS dot = sequential FMA
            const float dot = fmaf(pz, a.z, fmaf(py, a.y, __fmul_rn(px, a.x)));
            const float d2 = __fsub_rn(__fadd_rn(pn2, a.w), 2.0f * dot);
            if (d2 < vmin) {                         // rare after warmup
                if (abatch[cb*CHUNK + il] == pb) vmin = d2;
            }
        }
    }

    // ---- tau-select: 16 d-only pop-mins over the group's 32 lane minima.
    float tau;
    {
        float v = vmin;
        #pragma unroll
        for (int k = 0; k < KNN; ++k) {
            float d = v;
            d = fminf(d, __shfl_xor(d, 1));
            d = fminf(d, __shfl_xor(d, 2));
            d = fminf(d, __shfl_xor(d, 4));
            d = fminf(d, __shfl_xor(d, 8));
            d = fminf(d, __shfl_xor(d, 16));
            tau = d;
            if (v == d) v = FLT_MAX;    // remove popped (ties together: safe)
        }
    }

    // ---- filter pass over all 16 staged chunks; append qualifying global
    // idx (increasing order per lane). tau >= BIG -> fallback required.
    int cnt = 0;
    unsigned short* seg = &lbuf[g * (SLOTS*32) + c32];
    const int skip = !(tau < BIGF);                 // group-uniform
    for (int cb = 0; cb < NCHUNK; ++cb) {
        __syncthreads();
        #pragma unroll
        for (int j2 = 0; j2 < CHUNK/256; ++j2) lpos[j2*256 + tid] = pos4[cb*CHUNK + j2*256 + tid];
        __syncthreads();
        if (!skip) {
            #pragma unroll 4
            for (int t = 0; t < CHUNK/32; ++t) {
                const int il = t*32 + c32;
                const float4 a = lpos[il];
                const float dot = fmaf(pz, a.z, fmaf(py, a.y, __fmul_rn(px, a.x)));
                const float d2 = __fsub_rn(__fadd_rn(pn2, a.w), 2.0f * dot);
                if (d2 <= tau) {
                    const int gi = cb*CHUNK + il;
                    if (abatch[gi] == pb) {
                        if (cnt < SLOTS) seg[cnt*32] = (unsigned short)gi;
                        ++cnt;
                    }
                }
            }
        }
    }

    // ---- overflow guard (wave reconverged): group-or over 32 lanes.
    int ovf = skip | (cnt > SLOTS);
    ovf |= __shfl_xor(ovf, 1);
    ovf |= __shfl_xor(ovf, 2);
    ovf |= __shfl_xor(ovf, 4);
    ovf |= __shfl_xor(ovf, 8);
    ovf |= __shfl_xor(ovf, 16);

    float bd[KNN]; int bi[KNN];
    #pragma unroll
    for (int j = 0; j < KNN; ++j) { bd[j] = FLT_MAX; bi[j] = 0x7fffffff; }

    if (ovf) {
        // validated full insert-scan (rare; group-uniform; no cross-lane ops)
        for (int t = 0; t < MATOMS/32; ++t) {
            const int i = t*32 + c32;
            const float4 a = pos4[i];
            const int ab = abatch[i];
            const float dot = fmaf(pz, a.z, fmaf(py, a.y, __fmul_rn(px, a.x)));
            float d2 = __fsub_rn(__fadd_rn(pn2, a.w), 2.0f * dot);
            d2 = (ab == pb) ? d2 : BIGF;
            if (d2 < bd[KNN-1]) {
                float d = d2; int id = i;
                #pragma unroll
                for (int j = 0; j < KNN; ++j) {
                    const bool sw = d < bd[j];
                    const float od = bd[j]; const int oi = bi[j];
                    bd[j] = sw ? d  : bd[j];
                    bi[j] = sw ? id : bi[j];
                    d  = sw ? od : d;
                    id = sw ? oi : id;
                }
            }
        }
    } else {
        // ---- Phase C: exact top-16 of collected (appends were increasing-
        // index, so strict '<' d-only insert is tie-exact).
        for (int s = 0; s < cnt; ++s) {
            const int i = (int)seg[s*32];
            const float4 a = pos4[i];
            const float dot = fmaf(pz, a.z, fmaf(py, a.y, __fmul_rn(px, a.x)));
            const float d2 = __fsub_rn(__fadd_rn(pn2, a.w), 2.0f * dot);
            if (d2 < bd[KNN-1]) {
                float d = d2; int id = i;
                #pragma unroll
                for (int j = 0; j < KNN; ++j) {
                    const bool sw = d < bd[j];
                    const float od = bd[j]; const int oi = bi[j];
                    bd[j] = sw ? d  : bd[j];
                    bi[j] = sw ? id : bi[j];
                    d  = sw ? od : d;
                    id = sw ? oi : id;
                }
            }
        }
    }

    // ---- final merge: 16x pop-min over 32 lanes, lexicographic (d, idx);
    // all lanes receive idxk.
    int idxk[KNN];
    #pragma unroll
    for (int k = 0; k < KNN; ++k) {
        float d = bd[0]; int i = bi[0];
        #pragma unroll
        for (int m = 1; m <= 16; m <<= 1) {
            const float pd = __shfl_xor(d, m);
            const int   pi = __shfl_xor(i, m);
            const bool take = (pd < d) || (pd == d && pi < i);
            d = take ? pd : d;
            i = take ? pi : i;
        }
        idxk[k] = i;
        const bool win = (bd[0] == d) && (bi[0] == i);
        if (win) {
            #pragma unroll
            for (int j = 0; j < KNN-1; ++j) { bd[j] = bd[j+1]; bi[j] = bi[j+1]; }
            bd[KNN-1] = FLT_MAX; bi[KNN-1] = 0x7fffffff;
        }
    }

    // ---- Epilogue on lower 16 lanes of each group (exact validated numerics:
    // sequential k=0..15 accumulation per channel).
    if ((tid & 16) == 0) {
        const int c = tid & 15;                     // channel
        float ac0 = 0.0f, ac1 = 0.0f, ac2 = 0.0f;
        #pragma unroll
        for (int k = 0; k < KNN; ++k) {
            const int j = idxk[k];
            const float4 a = pos4[j];
            const float v0 = __fsub_rn(px, a.x);
            const float v1 = __fsub_rn(py, a.y);
            const float v2 = __fsub_rn(pz, a.z);
            // np: dists = sum(vecs*vecs, -1), sequential, no FMA (recomputed)
            const float dist = __fadd_rn(__fadd_rn(__fmul_rn(v0,v0), __fmul_rn(v1,v1)), __fmul_rn(v2,v2));
            const float w = 1.0f / __fadd_rn(dist, 1e-8f);   // power(x, -1.0)
            const float nv0 = __fmul_rn(v0, w);
            const float nv1 = __fmul_rn(v1, w);
            const float nv2 = __fmul_rn(v2, w);
            const float fc = tbuf[(size_t)j * CH + c];
            const float fw = __fmul_rn(fc, lwatt[k]);
            ac0 = fmaf(nv0, fw, ac0);
            ac1 = fmaf(nv1, fw, ac1);
            ac2 = fmaf(nv2, fw, ac2);
        }
        const float s = __fadd_rn(__fadd_rn(__fmul_rn(ac0,ac0), __fmul_rn(ac1,ac1)),
                                  __fmul_rn(ac2,ac2));
        const float fx = sqrtf(s);

        // output MLP: lane c computes channel c; values shared via width-16 shfl.
        float a1 = 0.0f;
        #pragma unroll
        for (int j = 0; j < CH; ++j) {
            const float fj = __shfl(fx, j, 16);
            a1 = fmaf(lw1t[j*CH + c], fj, a1);
        }
        const float g1 = leakyf(a1 + lb1[c]);

        float a2 = 0.0f;
        #pragma unroll
        for (int j = 0; j < CH; ++j) {
            const float gj = __shfl(g1, j, 16);
            a2 = fmaf(lw2t[j*CH + c], gj, a2);
        }
        const float g2 = leakyf(a2 + lb2[c]);

        float a3 = 0.0f;
        #pragma unroll
        for (int j = 0; j < CH; ++j) {
            const float gj = __shfl(g2, j, 16);
            a3 = fmaf(lw3t[j*CH + c], gj, a3);
        }
        out[(size_t)n*CH + c] = a3 + lb3[c];
    }
}

// ---------------------------------------------------------------------------
extern "C" void kernel_launch(void* const* d_in, const int* in_sizes, int n_in,
                              void* d_out, int out_size, void* d_ws, size_t ws_size,
                              hipStream_t stream)
{
    (void)in_sizes; (void)n_in; (void)out_size; (void)ws_size;
    const float* xyz        = (const float*)d_in[0];
    const float* atom_xyz   = (const float*)d_in[1];
    const float* atomtypes  = (const float*)d_in[2];
    const int*   batch      = (const int*)d_in[3];
    const int*   atom_batch = (const int*)d_in[4];
    const float* Wt1 = (const float*)d_in[5];
    const float* bt1 = (const float*)d_in[6];
    const float* Wt2 = (const float*)d_in[7];
    const float* bt2 = (const float*)d_in[8];
    const float* Wt3 = (const float*)d_in[9];
    const float* bt3 = (const float*)d_in[10];
    const float* Watt = (const float*)d_in[11];
    const float* We1 = (const float*)d_in[12];
    const float* be1 = (const float*)d_in[13];
    const float* We2 = (const float*)d_in[14];
    const float* be2 = (const float*)d_in[15];
    const float* We3 = (const float*)d_in[16];
    const float* be3 = (const float*)d_in[17];

    char* ws = (char*)d_ws;
    float4* pos4  = (float4*)ws;                          // 8192*16  = 131072 B
    float*  tbuf  = (float*)(ws + 131072);                // 8192*64  = 524288 B
    int*    abat  = (int*)(ws + 131072 + 524288);         // 8192*4   =  32768 B
    float*  out   = (float*)d_out;

    hipLaunchKernelGGL(prep_kernel, dim3(MATOMS/256), dim3(256), 0, stream,
                       atom_xyz, atomtypes, atom_batch,
                       Wt1, bt1, Wt2, bt2, Wt3, bt3,
                       pos4, tbuf, abat);
    hipLaunchKernelGGL(atom_main_kernel, dim3(NPTS/GROUPS_PER_BLOCK), dim3(256), 0, stream,
                       xyz, batch, pos4, tbuf, abat,
                       Watt, We1, be1, We2, be2, We3, be3,
                       out);
}

// Round 10
// 132.558 us; speedup vs baseline: 1.6031x; 1.1624x over previous
//
#include <hip/hip_runtime.h>
#include <cfloat>

#define NPTS   16384
#define MATOMS 8192
#define CH     16
#define ADIM   6
#define KNN    16
#define GROUPS_PER_BLOCK 8     // 32 lanes per point
#define BIGF   1e10f
#define SLOTS  16              // per-lane capacity (lambda~2.8 with 1/4-subset tau)
#define CHUNK  512
#define NCHUNK (MATOMS/CHUNK)  // 16
#define VMINC  4               // vmin subset = first 2048 atoms (validated r9 stat)
#define NPASS  (VMINC + NCHUNK) // 20

__device__ __forceinline__ float leakyf(float x) { return x >= 0.0f ? x : 0.2f * x; }

// ---------------------------------------------------------------------------
// Kernel A: per-atom feature MLP t = L3(L2(L1(atomtypes))) + packed pos4
// ---------------------------------------------------------------------------
__global__ void __launch_bounds__(256) prep_kernel(
    const float* __restrict__ atom_xyz,
    const float* __restrict__ atomtypes,
    const int*   __restrict__ atom_batch,
    const float* __restrict__ Wt1, const float* __restrict__ bt1,
    const float* __restrict__ Wt2, const float* __restrict__ bt2,
    const float* __restrict__ Wt3, const float* __restrict__ bt3,
    float4* __restrict__ pos4,
    float*  __restrict__ tbuf,
    int*    __restrict__ abatch)
{
    __shared__ float w1[CH*ADIM], w2[CH*CH], w3[CH*CH], bb1[CH], bb2[CH], bb3[CH];
    const int tid = threadIdx.x;
    if (tid < CH*ADIM) w1[tid] = Wt1[tid];
    if (tid < CH*CH)   { w2[tid] = Wt2[tid]; w3[tid] = Wt3[tid]; }
    if (tid < CH)      { bb1[tid] = bt1[tid]; bb2[tid] = bt2[tid]; bb3[tid] = bt3[tid]; }
    __syncthreads();
    const int m = blockIdx.x * 256 + tid;
    if (m >= MATOMS) return;

    float x[ADIM];
    #pragma unroll
    for (int j = 0; j < ADIM; ++j) x[j] = atomtypes[m*ADIM + j];

    float h0[CH], h1[CH], h2[CH];
    #pragma unroll
    for (int c = 0; c < CH; ++c) {
        float a = 0.0f;
        #pragma unroll
        for (int j = 0; j < ADIM; ++j) a = fmaf(w1[c*ADIM+j], x[j], a);
        h0[c] = leakyf(a + bb1[c]);
    }
    #pragma unroll
    for (int c = 0; c < CH; ++c) {
        float a = 0.0f;
        #pragma unroll
        for (int j = 0; j < CH; ++j) a = fmaf(w2[c*CH+j], h0[j], a);
        h1[c] = leakyf(a + bb2[c]);
    }
    #pragma unroll
    for (int c = 0; c < CH; ++c) {
        float a = 0.0f;
        #pragma unroll
        for (int j = 0; j < CH; ++j) a = fmaf(w3[c*CH+j], h1[j], a);
        h2[c] = leakyf(a + bb3[c]);
    }
    #pragma unroll
    for (int c = 0; c < CH; ++c) tbuf[m*CH + c] = h2[c];

    const float ax = atom_xyz[m*3+0], ay = atom_xyz[m*3+1], az = atom_xyz[m*3+2];
    // np: sum(a*a, -1) = ((ax^2 + ay^2) + az^2), no FMA contraction
    const float a2 = __fadd_rn(__fadd_rn(__fmul_rn(ax,ax), __fmul_rn(ay,ay)), __fmul_rn(az,az));
    pos4[m] = make_float4(ax, ay, az, a2);
    abatch[m] = atom_batch[m];
}

// ---------------------------------------------------------------------------
// Kernel B: 32 lanes/point, 8 groups/block, 2048 blocks.
//   Unified 20-pass loop, double-buffered LDS staging (pos4 + abatch):
//     barrier -> issue next-chunk loads -> scan cur buffer -> ds_write next.
//   Passes 0..3: per-lane lhs-min over 2048-atom subset (lhs = d2 - pn2 with
//     one rounding; filter margin analysis: |d2-(pn2+lhs)| <= ~2.2e-3).
//   Pass 4 start: tau = 16 pop-mins over 32 lane minima; tauf = tau + slack.
//     Validity: >=16 distinct in-batch atoms have lhs <= tau, so every true
//     top-16 atom has lhs <= tau + 2*err <= tauf  -> filter is a superset.
//   Passes 4..19: lean filter (5 VALU/candidate), append idx to lane seg.
//   Overflow/empty guard -> validated full insert-scan fallback.
//   Phase C: EXACT d2 recompute + validated insert + lexicographic merge
//   Epilogue (lower 16 lanes): per-channel contraction + shuffle MLP
// ---------------------------------------------------------------------------
__global__ void __launch_bounds__(256) atom_main_kernel(
    const float* __restrict__ xyz,
    const int*   __restrict__ batch,
    const float4* __restrict__ pos4,
    const float* __restrict__ tbuf,
    const int*   __restrict__ abatch,
    const float* __restrict__ Watt,
    const float* __restrict__ We1, const float* __restrict__ be1,
    const float* __restrict__ We2, const float* __restrict__ be2,
    const float* __restrict__ We3, const float* __restrict__ be3,
    float* __restrict__ out)
{
    __shared__ float lw1t[CH*CH], lw2t[CH*CH], lw3t[CH*CH];
    __shared__ float lb1[CH], lb2[CH], lb3[CH], lwatt[KNN];
    __shared__ unsigned short lbuf[GROUPS_PER_BLOCK * SLOTS * 32];
    __shared__ float4 lpos[2][CHUNK];
    __shared__ int    lbat[2][CHUNK];
    const int tid = threadIdx.x;
    lw1t[tid] = We1[(tid & 15)*CH + (tid >> 4)];
    lw2t[tid] = We2[(tid & 15)*CH + (tid >> 4)];
    lw3t[tid] = We3[(tid & 15)*CH + (tid >> 4)];
    if (tid < CH) { lb1[tid] = be1[tid]; lb2[tid] = be2[tid]; lb3[tid] = be3[tid]; lwatt[tid] = Watt[tid]; }

    const int c32 = tid & 31;
    const int grp = tid >> 5;
    const int n   = blockIdx.x * GROUPS_PER_BLOCK + grp;

    const float px = xyz[n*3+0], py = xyz[n*3+1], pz = xyz[n*3+2];
    // np: sum(x*x, -1) sequential, no FMA
    const float pn2 = __fadd_rn(__fadd_rn(__fmul_rn(px,px), __fmul_rn(py,py)), __fmul_rn(pz,pz));
    const int pb = batch[n];

    // prologue: stage chunk 0 into buffer 0
    {
        const float4 q0 = pos4[tid];
        const float4 q1 = pos4[tid+256];
        const int    e0 = abatch[tid];
        const int    e1 = abatch[tid+256];
        lpos[0][tid] = q0; lpos[0][tid+256] = q1;
        lbat[0][tid] = e0; lbat[0][tid+256] = e1;
    }

    float vmin = FLT_MAX;
    float tauf = 0.0f;
    int   skip = 0;
    int   cnt  = 0;
    unsigned short* seg = &lbuf[grp * (SLOTS*32) + c32];

    for (int g = 0; g < NPASS; ++g) {
        const int cur = g & 1;
        __syncthreads();                     // buf[cur] ready; buf[cur^1] free
        // issue next-chunk loads AFTER the barrier (not drained by it)
        float4 q0, q1; int e0, e1;
        const bool pf = (g+1 < NPASS);
        if (pf) {
            const int nc = (g+1 < VMINC) ? (g+1) : (g+1-VMINC);
            const int base = nc*CHUNK;
            q0 = pos4[base+tid]; q1 = pos4[base+tid+256];
            e0 = abatch[base+tid]; e1 = abatch[base+tid+256];
        }
        if (g == VMINC) {
            // tau-select: 16 d-only pop-mins over 32 lane minima (lhs-space)
            float tau = FLT_MAX;
            float v = vmin;
            #pragma unroll
            for (int k = 0; k < KNN; ++k) {
                float d = v;
                d = fminf(d, __shfl_xor(d, 1));
                d = fminf(d, __shfl_xor(d, 2));
                d = fminf(d, __shfl_xor(d, 4));
                d = fminf(d, __shfl_xor(d, 8));
                d = fminf(d, __shfl_xor(d, 16));
                tau = d;
                if (v == d) v = FLT_MAX;     // remove popped (ties safe)
            }
            skip = !(tau < BIGF);            // group-uniform
            tauf = tau + (1e-5f*(fabsf(pn2) + fabsf(tau)) + 1e-2f);
        }
        if (g < VMINC) {
            // vmin scan (subset chunks 0..3)
            #pragma unroll 4
            for (int t = 0; t < CHUNK/32; ++t) {
                const int il = t*32 + c32;
                const float4 a = lpos[cur][il];
                const float dot = fmaf(pz, a.z, fmaf(py, a.y, __fmul_rn(px, a.x)));
                const float lhs = fmaf(-2.0f, dot, a.w);
                if (lhs < vmin) { if (lbat[cur][il] == pb) vmin = lhs; }
            }
        } else if (!skip) {
            // lean filter scan
            const int cb = g - VMINC;
            #pragma unroll 4
            for (int t = 0; t < CHUNK/32; ++t) {
                const int il = t*32 + c32;
                const float4 a = lpos[cur][il];
                const float dot = fmaf(pz, a.z, fmaf(py, a.y, __fmul_rn(px, a.x)));
                const float lhs = fmaf(-2.0f, dot, a.w);
                if (lhs <= tauf) {
                    if (lbat[cur][il] == pb) {
                        const int gi = cb*CHUNK + il;
                        if (cnt < SLOTS) seg[cnt*32] = (unsigned short)gi;
                        ++cnt;
                    }
                }
            }
        }
        if (pf) {                            // write-late: loads landed by now
            lpos[cur^1][tid] = q0; lpos[cur^1][tid+256] = q1;
            lbat[cur^1][tid] = e0; lbat[cur^1][tid+256] = e1;
        }
    }

    // ---- overflow guard (wave reconverged): group-or over 32 lanes.
    int ovf = skip | (cnt > SLOTS);
    ovf |= __shfl_xor(ovf, 1);
    ovf |= __shfl_xor(ovf, 2);
    ovf |= __shfl_xor(ovf, 4);
    ovf |= __shfl_xor(ovf, 8);
    ovf |= __shfl_xor(ovf, 16);

    float bd[KNN]; int bi[KNN];
    #pragma unroll
    for (int j = 0; j < KNN; ++j) { bd[j] = FLT_MAX; bi[j] = 0x7fffffff; }

    if (ovf) {
        // validated full insert-scan (rare; group-uniform; lane-local only)
        for (int t = 0; t < MATOMS/32; ++t) {
            const int i = t*32 + c32;
            const float4 a = pos4[i];
            const int ab = abatch[i];
            const float dot = fmaf(pz, a.z, fmaf(py, a.y, __fmul_rn(px, a.x)));
            float d2 = __fsub_rn(__fadd_rn(pn2, a.w), 2.0f * dot);
            d2 = (ab == pb) ? d2 : BIGF;
            if (d2 < bd[KNN-1]) {
                float d = d2; int id = i;
                #pragma unroll
                for (int j = 0; j < KNN; ++j) {
                    const bool sw = d < bd[j];
                    const float od = bd[j]; const int oi = bi[j];
                    bd[j] = sw ? d  : bd[j];
                    bi[j] = sw ? id : bi[j];
                    d  = sw ? od : d;
                    id = sw ? oi : id;
                }
            }
        }
    } else {
        // ---- Phase C: exact top-16 of collected (exact d2 recompute;
        // appends were increasing-index -> strict '<' insert is tie-exact).
        for (int s = 0; s < cnt; ++s) {
            const int i = (int)seg[s*32];
            const float4 a = pos4[i];
            const float dot = fmaf(pz, a.z, fmaf(py, a.y, __fmul_rn(px, a.x)));
            const float d2 = __fsub_rn(__fadd_rn(pn2, a.w), 2.0f * dot);
            if (d2 < bd[KNN-1]) {
                float d = d2; int id = i;
                #pragma unroll
                for (int j = 0; j < KNN; ++j) {
                    const bool sw = d < bd[j];
                    const float od = bd[j]; const int oi = bi[j];
                    bd[j] = sw ? d  : bd[j];
                    bi[j] = sw ? id : bi[j];
                    d  = sw ? od : d;
                    id = sw ? oi : id;
                }
            }
        }
    }

    // ---- final merge: 16x pop-min over 32 lanes, lexicographic (d, idx)
    int idxk[KNN];
    #pragma unroll
    for (int k = 0; k < KNN; ++k) {
        float d = bd[0]; int i = bi[0];
        #pragma unroll
        for (int m = 1; m <= 16; m <<= 1) {
            const float pd = __shfl_xor(d, m);
            const int   pi = __shfl_xor(i, m);
            const bool take = (pd < d) || (pd == d && pi < i);
            d = take ? pd : d;
            i = take ? pi : i;
        }
        idxk[k] = i;
        const bool win = (bd[0] == d) && (bi[0] == i);
        if (win) {
            #pragma unroll
            for (int j = 0; j < KNN-1; ++j) { bd[j] = bd[j+1]; bi[j] = bi[j+1]; }
            bd[KNN-1] = FLT_MAX; bi[KNN-1] = 0x7fffffff;
        }
    }

    // ---- Epilogue on lower 16 lanes (validated numerics, unchanged)
    if ((tid & 16) == 0) {
        const int c = tid & 15;
        float ac0 = 0.0f, ac1 = 0.0f, ac2 = 0.0f;
        #pragma unroll
        for (int k = 0; k < KNN; ++k) {
            const int j = idxk[k];
            const float4 a = pos4[j];
            const float v0 = __fsub_rn(px, a.x);
            const float v1 = __fsub_rn(py, a.y);
            const float v2 = __fsub_rn(pz, a.z);
            // np: dists = sum(vecs*vecs, -1), sequential, no FMA (recomputed)
            const float dist = __fadd_rn(__fadd_rn(__fmul_rn(v0,v0), __fmul_rn(v1,v1)), __fmul_rn(v2,v2));
            const float w = 1.0f / __fadd_rn(dist, 1e-8f);   // power(x, -1.0)
            const float nv0 = __fmul_rn(v0, w);
            const float nv1 = __fmul_rn(v1, w);
            const float nv2 = __fmul_rn(v2, w);
            const float fc = tbuf[(size_t)j * CH + c];
            const float fw = __fmul_rn(fc, lwatt[k]);
            ac0 = fmaf(nv0, fw, ac0);
            ac1 = fmaf(nv1, fw, ac1);
            ac2 = fmaf(nv2, fw, ac2);
        }
        const float s = __fadd_rn(__fadd_rn(__fmul_rn(ac0,ac0), __fmul_rn(ac1,ac1)),
                                  __fmul_rn(ac2,ac2));
        const float fx = sqrtf(s);

        float a1 = 0.0f;
        #pragma unroll
        for (int j = 0; j < CH; ++j) {
            const float fj = __shfl(fx, j, 16);
            a1 = fmaf(lw1t[j*CH + c], fj, a1);
        }
        const float g1 = leakyf(a1 + lb1[c]);

        float a2 = 0.0f;
        #pragma unroll
        for (int j = 0; j < CH; ++j) {
            const float gj = __shfl(g1, j, 16);
            a2 = fmaf(lw2t[j*CH + c], gj, a2);
        }
        const float g2 = leakyf(a2 + lb2[c]);

        float a3 = 0.0f;
        #pragma unroll
        for (int j = 0; j < CH; ++j) {
            const float gj = __shfl(g2, j, 16);
            a3 = fmaf(lw3t[j*CH + c], gj, a3);
        }
        out[(size_t)n*CH + c] = a3 + lb3[c];
    }
}

// ---------------------------------------------------------------------------
extern "C" void kernel_launch(void* const* d_in, const int* in_sizes, int n_in,
                              void* d_out, int out_size, void* d_ws, size_t ws_size,
                              hipStream_t stream)
{
    (void)in_sizes; (void)n_in; (void)out_size; (void)ws_size;
    const float* xyz        = (const float*)d_in[0];
    const float* atom_xyz   = (const float*)d_in[1];
    const float* atomtypes  = (const float*)d_in[2];
    const int*   batch      = (const int*)d_in[3];
    const int*   atom_batch = (const int*)d_in[4];
    const float* Wt1 = (const float*)d_in[5];
    const float* bt1 = (const float*)d_in[6];
    const float* Wt2 = (const float*)d_in[7];
    const float* bt2 = (const float*)d_in[8];
    const float* Wt3 = (const float*)d_in[9];
    const float* bt3 = (const float*)d_in[10];
    const float* Watt = (const float*)d_in[11];
    const float* We1 = (const float*)d_in[12];
    const float* be1 = (const float*)d_in[13];
    const float* We2 = (const float*)d_in[14];
    const float* be2 = (const float*)d_in[15];
    const float* We3 = (const float*)d_in[16];
    const float* be3 = (const float*)d_in[17];

    char* ws = (char*)d_ws;
    float4* pos4  = (float4*)ws;                          // 8192*16  = 131072 B
    float*  tbuf  = (float*)(ws + 131072);                // 8192*64  = 524288 B
    int*    abat  = (int*)(ws + 131072 + 524288);         // 8192*4   =  32768 B
    float*  out   = (float*)d_out;

    hipLaunchKernelGGL(prep_kernel, dim3(MATOMS/256), dim3(256), 0, stream,
                       atom_xyz, atomtypes, atom_batch,
                       Wt1, bt1, Wt2, bt2, Wt3, bt3,
                       pos4, tbuf, abat);
    hipLaunchKernelGGL(atom_main_kernel, dim3(NPTS/GROUPS_PER_BLOCK), dim3(256), 0, stream,
                       xyz, batch, pos4, tbuf, abat,
                       Watt, We1, be1, We2, be2, We3, be3,
                       out);
}